// Round 1
// baseline (1230.591 us; speedup 1.0000x reference)
//
#include <hip/hip_runtime.h>

#define N_RELS 16
#define N_BASES 8
#define HD 128
#define EPG 8
#define CHUNKS 32

// ---------------- bucketing: group edges by relation ----------------

__global__ void count_etype(const int* __restrict__ etype, int E, int* __restrict__ counts) {
    __shared__ int lh[N_RELS];
    if (threadIdx.x < N_RELS) lh[threadIdx.x] = 0;
    __syncthreads();
    for (int e = blockIdx.x * blockDim.x + threadIdx.x; e < E; e += gridDim.x * blockDim.x)
        atomicAdd(&lh[etype[e]], 1);
    __syncthreads();
    if (threadIdx.x < N_RELS) atomicAdd(&counts[threadIdx.x], lh[threadIdx.x]);
}

__global__ void scan16(const int* __restrict__ counts, int* __restrict__ offsets,
                       int* __restrict__ cursor) {
    if (threadIdx.x == 0 && blockIdx.x == 0) {
        int s = 0;
        for (int r = 0; r < N_RELS; r++) { offsets[r] = s; cursor[r] = s; s += counts[r]; }
        offsets[N_RELS] = s;
    }
}

__global__ void scatter_perm(const int* __restrict__ etype, int E,
                             int* __restrict__ cursor, int* __restrict__ perm) {
    __shared__ int lh[N_RELS];
    __shared__ int lbase[N_RELS];
    int t = threadIdx.x;
    if (t < N_RELS) lh[t] = 0;
    __syncthreads();
    int e = blockIdx.x * blockDim.x + t;
    int r = 0, lpos = 0;
    bool valid = e < E;
    if (valid) { r = etype[e]; lpos = atomicAdd(&lh[r], 1); }
    __syncthreads();
    if (t < N_RELS) lbase[t] = atomicAdd(&cursor[t], lh[t]);
    __syncthreads();
    if (valid) perm[lbase[r] + lpos] = e;
}

// ---------------- W[r] = sum_b coef[r,b] * V[b] (both layers) ----------------

__global__ void compute_W(const float* __restrict__ V1, const float* __restrict__ coef1,
                          const float* __restrict__ V2, const float* __restrict__ coef2,
                          float* __restrict__ W1, float* __restrict__ W2) {
    int l = blockIdx.x >> 4, r = blockIdx.x & 15;
    const float* V    = l ? V2 : V1;
    const float* coef = l ? coef2 : coef1;
    float* W = (l ? W2 : W1) + (size_t)r * (HD * HD);
    __shared__ float c[N_BASES];
    if (threadIdx.x < N_BASES) c[threadIdx.x] = coef[r * N_BASES + threadIdx.x];
    __syncthreads();
    for (int x = threadIdx.x; x < HD * HD; x += blockDim.x) {
        float s = 0.f;
#pragma unroll
        for (int b = 0; b < N_BASES; b++) s += c[b] * V[b * HD * HD + x];
        W[x] = s;
    }
}

// ---------------- edge kernel: msg = (norm*h[src]) @ W[r]; out[dst] += msg ----------------
// grid = 16 relations x CHUNKS; block = 256 (4 waves); each wave handles EPG edges/group.
// LDS: Ws 64KB + hs 16KB = 80KB -> 2 blocks/CU (same as 64KB: floor(160/80)=2).

__global__ __launch_bounds__(256) void edge_gemm(
    const float* __restrict__ hin, const float* __restrict__ W,
    const float* __restrict__ norm, const int* __restrict__ src,
    const int* __restrict__ dst, const int* __restrict__ perm,
    const int* __restrict__ offsets, float* __restrict__ out) {
    __shared__ float Ws[HD * HD];
    __shared__ float hs[4][EPG * HD];
    const int r = blockIdx.x & 15;
    const int chunk = blockIdx.x >> 4;
    const int t = threadIdx.x;

    const float* Wr = W + (size_t)r * (HD * HD);
    for (int x = t * 4; x < HD * HD; x += 256 * 4)
        *(float4*)&Ws[x] = *(const float4*)&Wr[x];
    __syncthreads();

    const int wave = t >> 6, lane = t & 63;
    float* hw = hs[wave];
    const int begin = offsets[r], end = offsets[r + 1];
    const int gw = chunk * 4 + wave;       // wave id within this relation
    const int stride = CHUNKS * 4;         // total waves per relation

    for (int base = begin + gw * EPG; base < end; base += stride * EPG) {
        int dv[EPG];
        bool valid[EPG];
#pragma unroll
        for (int j = 0; j < EPG; j++) {
            valid[j] = (base + j) < end;
            int e = valid[j] ? perm[base + j] : perm[base];
            int s = src[e];
            dv[j] = dst[e];
            float nv = valid[j] ? norm[e] : 0.f;
            // stage row h[s]*nv into this wave's LDS slab (coalesced 256B x2)
            hw[j * HD + lane]      = hin[(size_t)s * HD + lane] * nv;
            hw[j * HD + 64 + lane] = hin[(size_t)s * HD + 64 + lane] * nv;
        }

        float acc0[EPG], acc1[EPG];
#pragma unroll
        for (int j = 0; j < EPG; j++) { acc0[j] = 0.f; acc1[j] = 0.f; }

#pragma unroll 8
        for (int i = 0; i < HD; i++) {
            float w0 = Ws[i * HD + lane];        // 2-way bank alias: free
            float w1 = Ws[i * HD + 64 + lane];
#pragma unroll
            for (int j = 0; j < EPG; j++) {
                float hv = hw[j * HD + i];       // broadcast read
                acc0[j] = fmaf(hv, w0, acc0[j]);
                acc1[j] = fmaf(hv, w1, acc1[j]);
            }
        }

#pragma unroll
        for (int j = 0; j < EPG; j++) {
            if (valid[j]) {
                atomicAdd(&out[(size_t)dv[j] * HD + lane], acc0[j]);
                atomicAdd(&out[(size_t)dv[j] * HD + 64 + lane], acc1[j]);
            }
        }
    }
}

// ---------------- epilogue: x = (relu?)(x + bias) ----------------

__global__ void bias_act(float* __restrict__ x, const float* __restrict__ bias,
                         int n4, int relu) {
    int i = blockIdx.x * blockDim.x + threadIdx.x;
    if (i >= n4) return;
    float4 v = ((float4*)x)[i];
    const float4 b = ((const float4*)bias)[i & 31];   // 128 floats = 32 float4 per row
    v.x += b.x; v.y += b.y; v.z += b.z; v.w += b.w;
    if (relu) {
        v.x = fmaxf(v.x, 0.f); v.y = fmaxf(v.y, 0.f);
        v.z = fmaxf(v.z, 0.f); v.w = fmaxf(v.w, 0.f);
    }
    ((float4*)x)[i] = v;
}

// ---------------- launch ----------------

extern "C" void kernel_launch(void* const* d_in, const int* in_sizes, int n_in,
                              void* d_out, int out_size, void* d_ws, size_t ws_size,
                              hipStream_t stream) {
    const float* h     = (const float*)d_in[0];
    const float* norm  = (const float*)d_in[1];
    const int*   src   = (const int*)d_in[2];
    const int*   dst   = (const int*)d_in[3];
    const int*   etype = (const int*)d_in[4];
    const float* V1    = (const float*)d_in[5];
    const float* coef1 = (const float*)d_in[6];
    const float* bias1 = (const float*)d_in[7];
    const float* V2    = (const float*)d_in[8];
    const float* coef2 = (const float*)d_in[9];
    const float* bias2 = (const float*)d_in[10];
    const int N = in_sizes[0] / HD;
    const int E = in_sizes[2];
    float* out = (float*)d_out;

    char* ws = (char*)d_ws;
    size_t off = 0;
    auto alloc = [&](size_t bytes) {
        void* p = ws + off;
        off += (bytes + 255) & ~(size_t)255;
        return p;
    };
    float* W1      = (float*)alloc((size_t)N_RELS * HD * HD * sizeof(float));
    float* W2      = (float*)alloc((size_t)N_RELS * HD * HD * sizeof(float));
    float* h1      = (float*)alloc((size_t)N * HD * sizeof(float));
    int*   perm    = (int*)alloc((size_t)E * sizeof(int));
    int*   counts  = (int*)alloc(16 * sizeof(int));
    int*   offsets = (int*)alloc(17 * sizeof(int));
    int*   cursor  = (int*)alloc(16 * sizeof(int));
    (void)ws_size; (void)n_in; (void)out_size;

    hipMemsetAsync(counts, 0, 16 * sizeof(int), stream);
    hipMemsetAsync(h1, 0, (size_t)N * HD * sizeof(float), stream);
    hipMemsetAsync(out, 0, (size_t)N * HD * sizeof(float), stream);

    count_etype<<<(E + 255) / 256, 256, 0, stream>>>(etype, E, counts);
    scan16<<<1, 64, 0, stream>>>(counts, offsets, cursor);
    scatter_perm<<<(E + 255) / 256, 256, 0, stream>>>(etype, E, cursor, perm);
    compute_W<<<32, 256, 0, stream>>>(V1, coef1, V2, coef2, W1, W2);

    // layer 1: h1 = relu(scatter(msg) + bias1)
    edge_gemm<<<N_RELS * CHUNKS, 256, 0, stream>>>(h, W1, norm, src, dst, perm, offsets, h1);
    bias_act<<<(N * HD / 4 + 255) / 256, 256, 0, stream>>>(h1, bias1, N * HD / 4, 1);

    // layer 2: out = scatter(msg) + bias2
    edge_gemm<<<N_RELS * CHUNKS, 256, 0, stream>>>(h1, W2, norm, src, dst, perm, offsets, out);
    bias_act<<<(N * HD / 4 + 255) / 256, 256, 0, stream>>>(out, bias2, N * HD / 4, 0);
}